// Round 10
// baseline (129.317 us; speedup 1.0000x reference)
//
#include <hip/hip_runtime.h>
#include <math.h>

#define NKC 128
#define DH  64
#define NEX 1024
#define G3  192

// ws layout (floats)
#define XOFF    0         // 32*64   = 2048
#define KCIOFF  2048      // 32*128  = 4096
#define NHOFF   6144      // 32*128*64 = 262144   [b][i][d]
#define DPOFF   268288    // 32*64*128 = 262144   [b][d][i]  (TRANSPOSED)

__device__ __forceinline__ float sigf(float x) { return 1.0f / (1.0f + expf(-x)); }
__device__ __forceinline__ float dot4(float4 a, float4 b) {
    return fmaf(a.x, b.x, fmaf(a.y, b.y, fmaf(a.z, b.z, a.w * b.w)));
}

// ---------------------------------------------------------------------------
// k0: x only. 256 blocks (b x 8 d-chunks of 8) x 256 threads. (r0-verified)
// ---------------------------------------------------------------------------
__global__ __launch_bounds__(256) void k0_x(
    const float* __restrict__ ex, const float* __restrict__ su,
    const float* __restrict__ W_ex, float* __restrict__ ws)
{
    int t = threadIdx.x, wave = t >> 6, lane = t & 63;
    int b = blockIdx.x >> 3;
    int dbase = (blockIdx.x & 7) * 8;
    float sub = su[b];
    const float* exb = ex + (size_t)b * NEX;
    float er[16];
    #pragma unroll
    for (int i = 0; i < 16; ++i) er[i] = exb[lane + i * 64];
    #pragma unroll
    for (int p = 0; p < 2; ++p) {
        int d = dbase + wave * 2 + p;
        const float* wr = W_ex + (size_t)d * (2 * NEX);
        float a1 = 0.f, a2 = 0.f;
        #pragma unroll 8
        for (int i = 0; i < 16; ++i) {
            int k = lane + i * 64;
            a1 = fmaf(er[i], wr[k], a1);
            a2 = fmaf(er[i], wr[NEX + k], a2);
        }
        float v = sub * a1 + (1.0f - sub) * a2;
        #pragma unroll
        for (int off = 32; off; off >>= 1) v += __shfl_down(v, off, 64);
        if (lane == 0) ws[XOFF + b * DH + d] = v;
    }
}

// ---------------------------------------------------------------------------
// k1: kci + tgru + new_h + dpart. 256 blocks x 512 threads.
// FULL tgru weights (2x 52 KB) staged ONCE at kernel start (116 KB LDS of the
// 160 KB/CU) -> no ch-split, 3 barriers total, staging overlapped with kci.
// ---------------------------------------------------------------------------
#define K1_WHH  0        // 192*68 = 13056
#define K1_WIH  13056    // 13056 (fwA 64*68 overlays after gi is done)
#define K1_HT   26112    // 1024
#define K1_DLT  27136    // 1024
#define K1_XS   28160    // 64
#define K1_KRED 28224    // 512
#define K1_GIS  28736    // 192
#define K1_BHH3 28928    // 192
#define K1_KCIL 29120    // 16
#define K1_SM   29136    // 116544 B

__global__ __launch_bounds__(512) void k1_tgru(
    const float* __restrict__ h, const float* __restrict__ ex,
    const float* __restrict__ ex_graph,
    const float* __restrict__ tgru_wih, const float* __restrict__ tgru_whh,
    const float* __restrict__ tgru_bih, const float* __restrict__ tgru_bhh,
    const float* __restrict__ fpart_w, float* __restrict__ ws)
{
    int t = threadIdx.x, wave = t >> 6, lane = t & 63;
    int b = blockIdx.x >> 3;
    int i0 = (blockIdx.x & 7) * 16;

    __shared__ __align__(16) float sm[K1_SM];

    // ---- one-shot staging: full weights + h + biases + x (k0 done)
    for (int idx = t; idx < G3 * 16; idx += 512) {
        int row = idx >> 4, q = idx & 15;
        *(float4*)&sm[K1_WHH + row * 68 + 4 * q] =
            *(const float4*)&tgru_whh[row * DH + 4 * q];
        *(float4*)&sm[K1_WIH + row * 68 + 4 * q] =
            *(const float4*)&tgru_wih[row * DH + 4 * q];
    }
    // kci partials (longest-latency strided loads)
    {
        int i = t & 15, ks = t >> 4, kb = ks * 32;
        const float* exb = ex + (size_t)b * NEX;
        const float* eg = ex_graph + i0 + i;
        float a = 0.f;
        #pragma unroll 4
        for (int k = 0; k < 32; ++k)
            a = fmaf(exb[kb + k], eg[(size_t)(kb + k) * NKC], a);
        sm[K1_KRED + t] = a;
    }
    if (t < 256) {
        const float* hb = h + (size_t)(b * NKC + i0) * DH;
        *(float4*)&sm[K1_HT + t * 4] = *(const float4*)&hb[t * 4];
    }
    if (t < DH) sm[K1_XS + t] = ws[XOFF + b * DH + t];
    if (t < G3) sm[K1_BHH3 + t] = tgru_bhh[t];
    __syncthreads();   // barrier 0

    if (t < 16) {
        float s = 0.f;
        #pragma unroll
        for (int r = 0; r < 32; ++r) s += sm[K1_KRED + r * 16 + t];
        sm[K1_KCIL + t] = s;
        ws[KCIOFF + b * NKC + i0 + t] = s;
    }
    // ---- full-width gi + hh dots (no ch split)
    float giA = (t < G3) ? tgru_bih[t] : 0.f;
    if (t < G3) {
        #pragma unroll 4
        for (int q = 0; q < 16; ++q)
            giA += dot4(*(float4*)&sm[K1_WIH + t * 68 + 4 * q],
                        *(float4*)&sm[K1_XS + 4 * q]);
    }
    float ar[2], az[2], an[2];
    #pragma unroll
    for (int m = 0; m < 2; ++m) {
        ar[m] = sm[K1_BHH3 + lane];
        az[m] = sm[K1_BHH3 + 64 + lane];
        an[m] = sm[K1_BHH3 + 128 + lane];
    }
    #pragma unroll 4
    for (int q = 0; q < 16; ++q) {
        float4 wr_ = *(float4*)&sm[K1_WHH + lane * 68 + 4 * q];
        float4 wz_ = *(float4*)&sm[K1_WHH + (64 + lane) * 68 + 4 * q];
        float4 wn_ = *(float4*)&sm[K1_WHH + (128 + lane) * 68 + 4 * q];
        #pragma unroll
        for (int m = 0; m < 2; ++m) {
            float4 hk = *(float4*)&sm[K1_HT + (wave * 2 + m) * DH + 4 * q];  // bcast
            ar[m] += dot4(wr_, hk);
            az[m] += dot4(wz_, hk);
            an[m] += dot4(wn_, hk);
        }
    }
    if (t < G3) sm[K1_GIS + t] = giA;
    __syncthreads();   // barrier 1 (gis visible; wih68 dead from here)

    // ---- GRU epilogue (new_h -> ws, delta -> LDS) + fwA stage concurrently
    #pragma unroll
    for (int m = 0; m < 2; ++m) {
        int il = wave * 2 + m;
        float hval = sm[K1_HT + il * DH + lane];
        float r = sigf(sm[K1_GIS + lane] + ar[m]);
        float z = sigf(sm[K1_GIS + 64 + lane] + az[m]);
        float n = tanhf(sm[K1_GIS + 128 + lane] + r * an[m]);
        float th = (1.0f - z) * n + z * hval;
        float kv = sm[K1_KCIL + il];
        float nh = (1.0f - kv) * hval + kv * th;
        ws[NHOFF + (size_t)(b * NKC + i0 + il) * DH + lane] = nh;
        sm[K1_DLT + il * DH + lane] = kv * (th - hval);
    }
    float* fw68 = sm + K1_WIH;    // overlays wih68 (dead after gi)
    for (int idx = t; idx < 64 * 16; idx += 512) {
        int d = idx >> 4, q = idx & 15;
        *(float4*)&fw68[d * 68 + 4 * q] = *(const float4*)&fpart_w[d * 128 + 4 * q];
    }
    __syncthreads();   // barrier 2

    // ---- dpart = delta_h @ fpart_w[:, :64].T ; scattered store
    float acc[2] = {0.f, 0.f};
    #pragma unroll 4
    for (int q = 0; q < 16; ++q) {
        float4 w = *(float4*)&fw68[lane * 68 + 4 * q];
        #pragma unroll
        for (int m = 0; m < 2; ++m)
            acc[m] += dot4(w, *(float4*)&sm[K1_DLT + (wave * 2 + m) * DH + 4 * q]);
    }
    float* dpb = ws + DPOFF + (size_t)b * 8192 + (size_t)lane * NKC + i0;
    #pragma unroll
    for (int m = 0; m < 2; ++m) dpb[wave * 2 + m] = acc[m];
}

// ---------------------------------------------------------------------------
// kB: epart(regs) + partj + outj + kcj + ugru + h_out. 256 blocks x 512 thr.
// FULL ugru weights (104 KB) staged at kernel start -> latency hidden under
// epart/partj/outj; 4 barriers total; ~146 KB LDS.
// ---------------------------------------------------------------------------
#define KB_WIHU  0        // 192*68 = 13056
#define KB_WHHU  13056    // 13056 -> 26112
#define KB_FWB   26112    // 64*68 = 4352 (UL overlays after epart)
#define KB_WKT   30464    // 16*68 = 1088
#define KB_WJT   31552    // 16*132 = 2112
#define KB_PJS   33664    // 1024
#define KB_OUTJ  34688    // 1024
#define KB_NEWH  35712    // 1024
#define KB_KCIF  36736    // 128
#define KB_KCJ   36864    // 16
#define KB_BIH   36880    // 192
#define KB_BHH   37072    // 192
#define KB_SM    37264    // 149056 B

__global__ __launch_bounds__(512) void kB_update(
    const float* __restrict__ kc_gamma, const float* __restrict__ W_kc,
    const float* __restrict__ fpart_w, const float* __restrict__ fpart_b,
    const float* __restrict__ ulin_w, const float* __restrict__ ulin_b,
    const float* __restrict__ ugru_wih, const float* __restrict__ ugru_whh,
    const float* __restrict__ ugru_bih, const float* __restrict__ ugru_bhh,
    float* __restrict__ ws, float* __restrict__ out)
{
    int t = threadIdx.x, wave = t >> 6, lane = t & 63;
    int b = blockIdx.x >> 3;
    int j0 = (blockIdx.x & 7) * 16;

    __shared__ __align__(16) float sm[KB_SM];

    // ---- one-shot staging: FULL ugru weights + everything epart needs
    for (int idx = t; idx < G3 * 16; idx += 512) {
        int row = idx >> 4, q = idx & 15;
        *(float4*)&sm[KB_WIHU + row * 68 + 4 * q] =
            *(const float4*)&ugru_wih[row * DH + 4 * q];
        *(float4*)&sm[KB_WHHU + row * 68 + 4 * q] =
            *(const float4*)&ugru_whh[row * DH + 4 * q];
    }
    for (int idx = t; idx < 1024; idx += 512) {
        int d = idx >> 4, q = idx & 15;
        *(float4*)&sm[KB_FWB + d * 68 + 4 * q] =
            *(const float4*)&fpart_w[d * 128 + 64 + 4 * q];
    }
    for (int idx = t; idx < 1024; idx += 512) {
        int c = idx >> 4, jl = idx & 15;
        sm[KB_WKT + jl * 68 + c] = W_kc[(size_t)c * NKC + j0 + jl];
    }
    if (t < 256) {
        const float* nhp = ws + NHOFF + (size_t)(b * NKC + j0) * DH;
        *(float4*)&sm[KB_NEWH + t * 4] = *(const float4*)&nhp[t * 4];
    }
    if (t < NKC) sm[KB_KCIF + t] = ws[KCIOFF + b * NKC + t];
    if (t < G3) { sm[KB_BIH + t] = ugru_bih[t]; sm[KB_BHH + t] = ugru_bhh[t]; }
    float fpb = fpart_b[lane];
    float ulb = ulin_b[lane];
    __syncthreads();   // barrier 0

    // ---- epart in registers (producer == consumer: jl = wave*2+m, d = lane)
    float epv[2];
    #pragma unroll
    for (int m = 0; m < 2; ++m) {
        float a = fpb;
        #pragma unroll 4
        for (int q = 0; q < 16; ++q)
            a += dot4(*(float4*)&sm[KB_FWB + lane * 68 + 4 * q],
                      *(float4*)&sm[KB_WKT + (wave * 2 + m) * 68 + 4 * q]);
        epv[m] = a;
    }
    // wjT [jl][i] stride 132
    for (int idx = t; idx < 2048; idx += 512) {
        int i = idx >> 4, jl = idx & 15;
        sm[KB_WJT + jl * 132 + i] =
            sm[KB_KCIF + i] * sigf(kc_gamma[(size_t)i * NKC + j0 + jl]);
    }
    __syncthreads();   // barrier 1 (FWB dead; wjT visible)

    if (t < 16) {
        float s = 0.f;
        #pragma unroll 8
        for (int qi = 0; qi < 32; ++qi) {
            float4 v = *(float4*)&sm[KB_WJT + t * 132 + 4 * qi];
            s += v.x + v.y + v.z + v.w;
        }
        sm[KB_KCJ + t] = s;
    }
    // UL stage into FWB region (dead), concurrent with partj
    float* ul68 = sm + KB_FWB;
    for (int idx = t; idx < 64 * 16; idx += 512) {
        int d = idx >> 4, q = idx & 15;
        *(float4*)&ul68[d * 68 + 4 * q] = *(const float4*)&ulin_w[d * DH + 4 * q];
    }
    // ---- partj: dv straight from ws (lane-contiguous row, L2-resident)
    {
        const float* dprow = ws + DPOFF + (size_t)b * 8192 + (size_t)lane * NKC;
        float pa0 = 0.f, pa1 = 0.f;
        float ep0 = epv[0], ep1 = epv[1];
        #pragma unroll 8
        for (int qi = 0; qi < 32; ++qi) {
            float4 dv = *(const float4*)&dprow[4 * qi];
            float4 w0 = *(float4*)&sm[KB_WJT + (wave * 2 + 0) * 132 + 4 * qi];
            float4 w1 = *(float4*)&sm[KB_WJT + (wave * 2 + 1) * 132 + 4 * qi];
            pa0 = fmaf(fmaxf(dv.x + ep0, 0.f), w0.x, pa0);
            pa0 = fmaf(fmaxf(dv.y + ep0, 0.f), w0.y, pa0);
            pa0 = fmaf(fmaxf(dv.z + ep0, 0.f), w0.z, pa0);
            pa0 = fmaf(fmaxf(dv.w + ep0, 0.f), w0.w, pa0);
            pa1 = fmaf(fmaxf(dv.x + ep1, 0.f), w1.x, pa1);
            pa1 = fmaf(fmaxf(dv.y + ep1, 0.f), w1.y, pa1);
            pa1 = fmaf(fmaxf(dv.z + ep1, 0.f), w1.z, pa1);
            pa1 = fmaf(fmaxf(dv.w + ep1, 0.f), w1.w, pa1);
        }
        sm[KB_PJS + (wave * 2 + 0) * DH + lane] = pa0;
        sm[KB_PJS + (wave * 2 + 1) * DH + lane] = pa1;
    }
    __syncthreads();   // barrier 2 (UL + PJS visible)

    // ---- outj = relu(pj @ ulin_w.T + b)
    float oa[2] = {ulb, ulb};
    #pragma unroll 4
    for (int q = 0; q < 16; ++q) {
        float4 uv = *(float4*)&ul68[lane * 68 + 4 * q];
        #pragma unroll
        for (int m = 0; m < 2; ++m)
            oa[m] += dot4(uv, *(float4*)&sm[KB_PJS + (wave * 2 + m) * DH + 4 * q]);
    }
    #pragma unroll
    for (int m = 0; m < 2; ++m)
        sm[KB_OUTJ + (wave * 2 + m) * DH + lane] = fmaxf(oa[m], 0.f);
    __syncthreads();   // barrier 3 (OUTJ visible)

    // ---- ugru: full-width, weights long since resident
    float gir[2], giz[2], gin[2], ghr[2], ghz[2], ghn[2];
    #pragma unroll
    for (int m = 0; m < 2; ++m)
        gir[m] = giz[m] = gin[m] = ghr[m] = ghz[m] = ghn[m] = 0.f;
    #pragma unroll 2
    for (int q = 0; q < 16; ++q) {
        float4 wir = *(float4*)&sm[KB_WIHU + lane * 68 + 4 * q];
        float4 wiz = *(float4*)&sm[KB_WIHU + (64 + lane) * 68 + 4 * q];
        float4 win = *(float4*)&sm[KB_WIHU + (128 + lane) * 68 + 4 * q];
        float4 wwr = *(float4*)&sm[KB_WHHU + lane * 68 + 4 * q];
        float4 wwz = *(float4*)&sm[KB_WHHU + (64 + lane) * 68 + 4 * q];
        float4 wwn = *(float4*)&sm[KB_WHHU + (128 + lane) * 68 + 4 * q];
        #pragma unroll
        for (int m = 0; m < 2; ++m) {
            int jl = wave * 2 + m;
            float4 ov = *(float4*)&sm[KB_OUTJ + jl * DH + 4 * q];   // bcast
            float4 nv = *(float4*)&sm[KB_NEWH + jl * DH + 4 * q];   // bcast
            gir[m] += dot4(wir, ov);
            giz[m] += dot4(wiz, ov);
            gin[m] += dot4(win, ov);
            ghr[m] += dot4(wwr, nv);
            ghz[m] += dot4(wwz, nv);
            ghn[m] += dot4(wwn, nv);
        }
    }
    #pragma unroll
    for (int m = 0; m < 2; ++m) {
        int jl = wave * 2 + m;
        float r = sigf(gir[m] + sm[KB_BIH + lane] + ghr[m] + sm[KB_BHH + lane]);
        float z = sigf(giz[m] + sm[KB_BIH + 64 + lane] + ghz[m] + sm[KB_BHH + 64 + lane]);
        float n = tanhf(gin[m] + sm[KB_BIH + 128 + lane] +
                        r * (ghn[m] + sm[KB_BHH + 128 + lane]));
        float nh = sm[KB_NEWH + jl * DH + lane];
        float uh = (1.0f - z) * n + z * nh;
        float kj = sm[KB_KCJ + jl];
        out[(size_t)(b * NKC + j0 + jl) * DH + lane] = (1.0f - kj) * nh + kj * uh;
    }
}

extern "C" void kernel_launch(void* const* d_in, const int* in_sizes, int n_in,
                              void* d_out, int out_size, void* d_ws, size_t ws_size,
                              hipStream_t stream) {
    const float* h        = (const float*)d_in[0];
    const float* ex       = (const float*)d_in[1];
    const float* su       = (const float*)d_in[2];
    const float* ex_graph = (const float*)d_in[3];
    const float* kc_gamma = (const float*)d_in[4];
    const float* W_ex     = (const float*)d_in[5];
    const float* W_kc     = (const float*)d_in[6];
    const float* tgru_wih = (const float*)d_in[7];
    const float* tgru_whh = (const float*)d_in[8];
    const float* tgru_bih = (const float*)d_in[9];
    const float* tgru_bhh = (const float*)d_in[10];
    const float* fpart_w  = (const float*)d_in[11];
    const float* fpart_b  = (const float*)d_in[12];
    const float* ulin_w   = (const float*)d_in[13];
    const float* ulin_b   = (const float*)d_in[14];
    const float* ugru_wih = (const float*)d_in[15];
    const float* ugru_whh = (const float*)d_in[16];
    const float* ugru_bih = (const float*)d_in[17];
    const float* ugru_bhh = (const float*)d_in[18];
    float* ws  = (float*)d_ws;
    float* out = (float*)d_out;

    hipLaunchKernelGGL(k0_x, dim3(256), dim3(256), 0, stream,
                       ex, su, W_ex, ws);
    hipLaunchKernelGGL(k1_tgru, dim3(256), dim3(512), 0, stream,
                       h, ex, ex_graph, tgru_wih, tgru_whh, tgru_bih,
                       tgru_bhh, fpart_w, ws);
    hipLaunchKernelGGL(kB_update, dim3(256), dim3(512), 0, stream,
                       kc_gamma, W_kc, fpart_w, fpart_b, ulin_w, ulin_b,
                       ugru_wih, ugru_whh, ugru_bih, ugru_bhh, ws, out);
}